// Round 1
// 594.279 us; speedup vs baseline: 1.1141x; 1.1141x over previous
//
#include <hip/hip_runtime.h>
#include <stdint.h>

// ---- problem constants ----
#define B_N   2
#define HQ_N  32
#define HKV_N 8
#define QL_N  1024
#define SL_N  4096
#define DH_N  128
#define ROPE_N 64
#define RANK_N 512
#define DEFF_N 576   // RANK + ROPE

typedef _Float16 f16;
typedef _Float16 half8 __attribute__((ext_vector_type(8)));
typedef float floatx16 __attribute__((ext_vector_type(16)));
typedef int int2v __attribute__((ext_vector_type(2)));

union H8 { half8 h; uint64_t q[2]; };
union H4 { f16 h[4]; uint64_t q; };
union PKU { f16 h[2]; uint32_t u; };
union BFU { uint32_t u[4]; half8 h; };

// ---------------------------------------------------------------------------
// prep 1: fp32 -> fp16 convert of C_kv_t2 and K_rope_t2
// ---------------------------------------------------------------------------
__global__ __launch_bounds__(256) void k_convert(const float* __restrict__ C,
                                                 const float* __restrict__ Kr,
                                                 f16* __restrict__ Cf,
                                                 f16* __restrict__ Krf) {
  const size_t NC = (size_t)B_N * SL_N * RANK_N;            // 4194304
  size_t idx = ((size_t)blockIdx.x * 256 + threadIdx.x) * 8; // covers 8388608
  const float* src;
  f16* dst;
  if (idx < NC) { src = C + idx;        dst = Cf + idx; }
  else          { src = Kr + (idx - NC); dst = Krf + (idx - NC); }
  float4 a = *(const float4*)(src);
  float4 b = *(const float4*)(src + 4);
  H8 o;
  o.h[0] = (f16)a.x; o.h[1] = (f16)a.y; o.h[2] = (f16)a.z; o.h[3] = (f16)a.w;
  o.h[4] = (f16)b.x; o.h[5] = (f16)b.y; o.h[6] = (f16)b.z; o.h[7] = (f16)b.w;
  *(half8*)dst = o.h;
}

// ---------------------------------------------------------------------------
// prep 2: M2T[c][d] (576 x 128, f16): Q_eff = Q @ M2.
// ---------------------------------------------------------------------------
__global__ __launch_bounds__(256) void k_m2(const float* __restrict__ Ul,
                                            const float* __restrict__ WUK,
                                            f16* __restrict__ M2T) {
  int idx = blockIdx.x * 256 + threadIdx.x;   // < 73728
  int c = idx >> 7, d = idx & 127;
  float v = 0.f;
  if (c < 512) {
    if (d >= 64) {
      int i = d - 64;
      for (int j = 0; j < 64; ++j) v += Ul[j * 64 + i] * WUK[j * 512 + c];
    }
  } else {
    if (d < 64) v = Ul[(c - 512) * 64 + d];
  }
  M2T[idx] = (f16)v;
}

// ---------------------------------------------------------------------------
// prep 3: Qeff = f16(Q) @ M2  via MFMA.  M=65536, K=128, N=576.
// grid = 512 m-tiles(128); each block loops the 3 n-chunks(192) over one
// staged Q tile (Q read once, not 3x) and stores the accumulator directly
// (each 32-lane half writes 64 contiguous bytes -> coalesced).
// ---------------------------------------------------------------------------
__global__ __launch_bounds__(256) void k_qeff(const float* __restrict__ Q,
                                              const f16* __restrict__ M2T,
                                              f16* __restrict__ Qeff) {
  __shared__ __align__(16) f16 qs[128 * 132];  // 33792 B
  int t = threadIdx.x;
  int wave = t >> 6, lane = t & 63, l31 = lane & 31, lhi = lane >> 5;
  size_t m0 = (size_t)blockIdx.x * 128;
  // stage Q tile (fp32 -> f16) once
#pragma unroll
  for (int i = 0; i < 16; i++) {
    int flat = i * 256 + t; int row = flat >> 5, seg = flat & 31;
    float4 v = *(const float4*)(Q + (m0 + row) * DH_N + seg * 4);
    H4 o; o.h[0] = (f16)v.x; o.h[1] = (f16)v.y; o.h[2] = (f16)v.z; o.h[3] = (f16)v.w;
    *(uint64_t*)(qs + row * 132 + seg * 4) = o.q;
  }
  __syncthreads();
  // hoist A-fragments (reused by all 3 n-chunks)
  H8 afr[8];
#pragma unroll
  for (int kk = 0; kk < 8; ++kk) {
    const uint64_t* pa = (const uint64_t*)(qs + (wave * 32 + l31) * 132 + kk * 16 + lhi * 8);
    afr[kk].q[0] = pa[0]; afr[kk].q[1] = pa[1];
  }
  for (int nb = 0; nb < 3; ++nb) {
    int n0 = nb * 192;
    floatx16 acc[6];
#pragma unroll
    for (int ct = 0; ct < 6; ct++)
#pragma unroll
      for (int r = 0; r < 16; r++) acc[ct][r] = 0.f;
#pragma unroll
    for (int kk = 0; kk < 8; ++kk) {
#pragma unroll
      for (int ct = 0; ct < 6; ct++) {
        H8 bf; bf.h = *(const half8*)(M2T + (size_t)(n0 + ct * 32 + l31) * 128 + kk * 16 + lhi * 8);
        acc[ct] = __builtin_amdgcn_mfma_f32_32x32x16_f16(afr[kk].h, bf.h, acc[ct], 0, 0, 0);
      }
    }
    // direct store: row = m0 + wave*32 + rowmap(r), col = n0 + ct*32 + l31
#pragma unroll
    for (int ct = 0; ct < 6; ct++)
#pragma unroll
      for (int r = 0; r < 16; r++) {
        int row = (r & 3) + 8 * (r >> 2) + 4 * lhi;
        Qeff[(m0 + wave * 32 + row) * DEFF_N + n0 + ct * 32 + l31] = (f16)acc[ct][r];
      }
  }
}

// ---------------------------------------------------------------------------
// prep 4: CW^T[b][c][s] = (C[b] @ W_UV)^T in fp16, via MFMA.
// grid = 256 = b(2) x 128 s-tiles(32).  out[s][c] = Cf(A)[s][r] . WUV(B)[r][c]
// A-frags: contiguous half8 from Cf (global, L2).  B-frags: coalesced
// per-column f32 loads of WUV (256 KB, L2-hot).  LDS only for the 17 KB
// output transpose.
// ---------------------------------------------------------------------------
__global__ __launch_bounds__(256) void k_cw(const f16* __restrict__ Cf,
                                            const float* __restrict__ WUV,
                                            f16* __restrict__ CWT) {
  __shared__ float ot[32 * 132];   // 16896 B
  int t = threadIdx.x;
  int wave = t >> 6, lane = t & 63, l31 = lane & 31, lhi = lane >> 5;
  int b = blockIdx.x >> 7, st = blockIdx.x & 127;
  int s0 = st * 32;
  const f16* Cb = Cf + ((size_t)b * SL_N + s0) * RANK_N;
  floatx16 acc;
#pragma unroll
  for (int r = 0; r < 16; r++) acc[r] = 0.f;
#pragma unroll 4
  for (int kk = 0; kk < 32; ++kk) {
    H8 af; af.h = *(const half8*)(Cb + (size_t)l31 * RANK_N + kk * 16 + lhi * 8);
    H8 bf;
#pragma unroll
    for (int j = 0; j < 8; j++)
      bf.h[j] = (f16)WUV[(size_t)(kk * 16 + lhi * 8 + j) * DH_N + wave * 32 + l31];
    acc = __builtin_amdgcn_mfma_f32_32x32x16_f16(af.h, bf.h, acc, 0, 0, 0);
  }
  // acc: row = s_local = (r&3)+8*(r>>2)+4*lhi, col = c = wave*32+l31
#pragma unroll
  for (int r = 0; r < 16; r++)
    ot[((r & 3) + 8 * (r >> 2) + 4 * lhi) * 132 + wave * 32 + l31] = acc[r];
  __syncthreads();
  int c = t >> 1, sh = t & 1;
  H8 o0, o1;
#pragma unroll
  for (int j = 0; j < 8; j++) o0.h[j] = (f16)ot[(sh * 16 + j) * 132 + c];
#pragma unroll
  for (int j = 0; j < 8; j++) o1.h[j] = (f16)ot[(sh * 16 + 8 + j) * 132 + c];
  f16* dst = CWT + ((size_t)b * DH_N + c) * SL_N + s0 + sh * 16;
  *(half8*)dst = o0.h;
  *(half8*)(dst + 8) = o1.h;
}

// ---------------------------------------------------------------------------
// flash kernel: S^T formulation, online softmax, PV vs precomputed CW^T.
// 256 threads / 4 waves, s-tile 32, SINGLE kbuf (rope merged, KROW=580),
// 2-barrier pipelined loop.  This round: P^T goes through registers
// (pack + permlane32_swap, T12) instead of LDS; strict defer-rescale.
// LDS 55552 B.  grid = 512 = (b, h, q-tile 128).
// ---------------------------------------------------------------------------
#define KROW 580   // halves; 1160 B stride = 290 dw = 2 mod 32 -> 2-way (free)
#define CROW 36

__global__ __launch_bounds__(256, 2) void k_flash(
    const f16* __restrict__ Qeff, const f16* __restrict__ Cf,
    const f16* __restrict__ Krf, const f16* __restrict__ CWT,
    float* __restrict__ out) {
  __shared__ __align__(16) char smem[55552];
  f16* kbuf  = (f16*)smem;                    // [32][KROW] 37120 B (cols 512..575 = rope)
  f16* cbuf0 = (f16*)(smem + 37120);          // [128][CROW] 9216 B
  f16* cbuf1 = (f16*)(smem + 46336);
  float* ot  = (float*)smem;                  // epilogue [64][133] 34048 B

  int t = threadIdx.x;
  int wave = t >> 6, lane = t & 63, l31 = lane & 31, lhi = lane >> 5;
  int qt = blockIdx.x & 7; int h = (blockIdx.x >> 3) & 31; int b = blockIdx.x >> 8;
  int kv = h >> 2;
  int qloc = wave * 32 + l31;

  const f16* Cb = Cf + (size_t)b * SL_N * RANK_N;
  const f16* Kb = Krf + (size_t)(b * HKV_N + kv) * SL_N * ROPE_N;
  const f16* Wb = CWT + (size_t)b * DH_N * SL_N;

  // persistent Q fragments (B-operand): lane holds Q_eff[qbase+qloc][kk*16+lhi*8 ..+7]
  half8 qf[36];
  {
    const f16* qrow = Qeff + ((size_t)(b * HQ_N + h) * QL_N + qt * 128 + qloc) * DEFF_N + lhi * 8;
#pragma unroll
    for (int kk = 0; kk < 36; kk++) qf[kk] = *(const half8*)(qrow + kk * 16);
  }

  floatx16 oacc[4];
#pragma unroll
  for (int ct = 0; ct < 4; ct++)
#pragma unroll
    for (int r = 0; r < 16; r++) oacc[ct][r] = 0.f;
  float m_run = -1e30f, l_run = 0.f;

  int rs = t >> 3, rch = t & 7;   // rope staging: row rs, col 512 + rch*8
  int cA = t >> 2, cch = t & 3;   // cwt staging: rows cA and 64+cA, cols cch*8

  // ---- preload tile 0 ----
  {
#pragma unroll
    for (int i = 0; i < 8; i++) {
      int s = i * 4 + wave;
      __builtin_amdgcn_global_load_lds(
          (const __attribute__((address_space(1))) void*)(Cb + (size_t)s * RANK_N + lane * 8),
          (__attribute__((address_space(3))) void*)(kbuf + s * KROW), 16, 0, 0);
    }
    H8 rp, c0, c1;
    rp.h = *(const half8*)(Kb + (size_t)rs * ROPE_N + rch * 8);
    c0.h = *(const half8*)(Wb + (size_t)cA * SL_N + cch * 8);
    c1.h = *(const half8*)(Wb + (size_t)(64 + cA) * SL_N + cch * 8);
    uint64_t* d = (uint64_t*)(kbuf + rs * KROW + 512 + rch * 8);
    d[0] = rp.q[0]; d[1] = rp.q[1];
    uint64_t* e0 = (uint64_t*)(cbuf0 + cA * CROW + cch * 8);
    e0[0] = c0.q[0]; e0[1] = c0.q[1];
    uint64_t* e1 = (uint64_t*)(cbuf0 + (64 + cA) * CROW + cch * 8);
    e1[0] = c1.q[0]; e1[1] = c1.q[1];
  }
  __syncthreads();

  for (int it = 0; it < 128; ++it) {
    f16* cc = (it & 1) ? cbuf1 : cbuf0;
    f16* cn = (it & 1) ? cbuf0 : cbuf1;
    bool pre = (it + 1) < 128;
    int s0n = (it + 1) * 32;
    H8 rp, c0, c1;
    if (pre) {  // register prefetch (in flight during S^T)
      rp.h = *(const half8*)(Kb + (size_t)(s0n + rs) * ROPE_N + rch * 8);
      c0.h = *(const half8*)(Wb + (size_t)cA * SL_N + s0n + cch * 8);
      c1.h = *(const half8*)(Wb + (size_t)(64 + cA) * SL_N + s0n + cch * 8);
    }

    // ---- S^T = K_eff(A) . Q^T(B) : only phase reading kbuf ----
    floatx16 sa;
#pragma unroll
    for (int r = 0; r < 16; r++) sa[r] = 0.f;
    const f16* ka = kbuf + l31 * KROW + lhi * 8;
#pragma unroll
    for (int kk = 0; kk < 36; kk++) {
      H8 a0;
      const uint64_t* p0 = (const uint64_t*)(ka + kk * 16);
      a0.q[0] = p0[0]; a0.q[1] = p0[1];
      sa = __builtin_amdgcn_mfma_f32_32x32x16_f16(a0.h, qf[kk], sa, 0, 0, 0);
    }
    __syncthreads();   // barrier A: kbuf free; prefetch regs landed

    // ---- issue DMA for tile i+1 + commit reg prefetches (flight covered below) ----
    if (pre) {
#pragma unroll
      for (int i = 0; i < 8; i++) {
        int s = i * 4 + wave;
        __builtin_amdgcn_global_load_lds(
            (const __attribute__((address_space(1))) void*)(Cb + (size_t)(s0n + s) * RANK_N + lane * 8),
            (__attribute__((address_space(3))) void*)(kbuf + s * KROW), 16, 0, 0);
      }
      uint64_t* d = (uint64_t*)(kbuf + rs * KROW + 512 + rch * 8);
      d[0] = rp.q[0]; d[1] = rp.q[1];
      uint64_t* e0 = (uint64_t*)(cn + cA * CROW + cch * 8);
      e0[0] = c0.q[0]; e0[1] = c0.q[1];
      uint64_t* e1 = (uint64_t*)(cn + (64 + cA) * CROW + cch * 8);
      e1[0] = c1.q[0]; e1[1] = c1.q[1];
    }

    // ---- online softmax: q in lane, s in regs (+ partner lane via xor32) ----
    float mt = -1e30f;
#pragma unroll
    for (int r = 0; r < 16; r++) mt = fmaxf(mt, sa[r]);
    mt = fmaxf(mt, __shfl_xor(mt, 32, 64));
    // strict defer-rescale: alpha would be exactly 1 for every lane unless
    // some lane's tile-max exceeds its running max (numerically identical).
    if (__any(mt > m_run)) {
      float m_new = fmaxf(m_run, mt);
      float alpha = __expf(m_run - m_new);
      l_run *= alpha;
#pragma unroll
      for (int ct = 0; ct < 4; ct++)
#pragma unroll
        for (int r = 0; r < 16; r++) oacc[ct][r] *= alpha;
      m_run = m_new;
    }
    float psum = 0.f;
#pragma unroll
    for (int r = 0; r < 16; r++) { sa[r] = __expf(sa[r] - m_run); psum += sa[r]; }
    psum += __shfl_xor(psum, 32, 64);
    l_run += psum;

    // ---- build PV B-fragments in-register (T12: pack + permlane32_swap) ----
    // sa[r] = P[q=l31][s=(r&3)+8*(r>>2)+4*lhi]; B-frag needs P[q=l31][s=ks*16+lhi*8+j]
    uint32_t pk[8];
#pragma unroll
    for (int g = 0; g < 8; ++g) {
      PKU pu; pu.h[0] = (f16)sa[2 * g]; pu.h[1] = (f16)sa[2 * g + 1];
      pk[g] = pu.u;
    }
    {
      int2v r0 = __builtin_amdgcn_permlane32_swap((int)pk[0], (int)pk[2], false, false);
      pk[0] = (uint32_t)r0.x; pk[2] = (uint32_t)r0.y;
      int2v r1 = __builtin_amdgcn_permlane32_swap((int)pk[1], (int)pk[3], false, false);
      pk[1] = (uint32_t)r1.x; pk[3] = (uint32_t)r1.y;
      int2v r2 = __builtin_amdgcn_permlane32_swap((int)pk[4], (int)pk[6], false, false);
      pk[4] = (uint32_t)r2.x; pk[6] = (uint32_t)r2.y;
      int2v r3 = __builtin_amdgcn_permlane32_swap((int)pk[5], (int)pk[7], false, false);
      pk[5] = (uint32_t)r3.x; pk[7] = (uint32_t)r3.y;
    }
    BFU b0, b1;
    b0.u[0] = pk[0]; b0.u[1] = pk[1]; b0.u[2] = pk[2]; b0.u[3] = pk[3];
    b1.u[0] = pk[4]; b1.u[1] = pk[5]; b1.u[2] = pk[6]; b1.u[3] = pk[7];

    // ---- PV: out^T = CW^T(A) . P^T(B), K = 32 s (2 ksteps) ----
#pragma unroll
    for (int ks = 0; ks < 2; ++ks) {
      half8 bfh = ks ? b1.h : b0.h;
#pragma unroll
      for (int ct = 0; ct < 4; ct++) {
        H8 af;
        const uint64_t* pa = (const uint64_t*)(cc + (ct * 32 + l31) * CROW + ks * 16 + lhi * 8);
        af.q[0] = pa[0]; af.q[1] = pa[1];
        oacc[ct] = __builtin_amdgcn_mfma_f32_32x32x16_f16(af.h, bfh, oacc[ct], 0, 0, 0);
      }
    }
    __syncthreads();   // barrier B: DMA + LDS commits visible for next S^T
  }

  // ---- epilogue: two q-halves through LDS, coalesced fp32 stores ----
  float inv = 1.0f / l_run;
  float* outp = out + ((size_t)(b * HQ_N + h) * QL_N + qt * 128) * DH_N;
#pragma unroll
  for (int p = 0; p < 2; ++p) {
    __syncthreads();
    if ((qloc >> 6) == p) {
      int lr = qloc & 63;
#pragma unroll
      for (int ct = 0; ct < 4; ct++)
#pragma unroll
        for (int r = 0; r < 16; r++) {
          int c = ct * 32 + (r & 3) + 8 * (r >> 2) + 4 * lhi;
          ot[lr * 133 + c] = oacc[ct][r] * inv;
        }
    }
    __syncthreads();
#pragma unroll
    for (int i = 0; i < 8; i++) {
      int flat = i * 256 + t; int q = flat >> 5, ch = flat & 31;
      float4 v;
      v.x = ot[q * 133 + ch * 4 + 0];
      v.y = ot[q * 133 + ch * 4 + 1];
      v.z = ot[q * 133 + ch * 4 + 2];
      v.w = ot[q * 133 + ch * 4 + 3];
      *(float4*)(outp + (size_t)(p * 64 + q) * DH_N + ch * 4) = v;
    }
  }
}

// ---------------------------------------------------------------------------
extern "C" void kernel_launch(void* const* d_in, const int* in_sizes, int n_in,
                              void* d_out, int out_size, void* d_ws, size_t ws_size,
                              hipStream_t stream) {
  (void)in_sizes; (void)n_in; (void)out_size; (void)ws_size;
  const float* Q   = (const float*)d_in[0];
  const float* C   = (const float*)d_in[1];
  const float* Kr  = (const float*)d_in[2];
  const float* Ul  = (const float*)d_in[3];
  const float* WUK = (const float*)d_in[4];
  const float* WUV = (const float*)d_in[5];
  float* out = (float*)d_out;
  char* ws = (char*)d_ws;
  // workspace carve (~94.4 MB)
  f16* Qeff = (f16*)ws;                   // 75497472 B
  f16* Cf   = (f16*)(ws + 75497472);      //  8388608 B
  f16* Krf  = (f16*)(ws + 83886080);      //  8388608 B
  f16* CWT  = (f16*)(ws + 92274688);      //  2097152 B
  f16* M2T  = CWT;  // aliased: consumed by k_qeff, then overwritten by k_cw

  hipLaunchKernelGGL(k_convert, dim3(4096), dim3(256), 0, stream, C, Kr, Cf, Krf);
  hipLaunchKernelGGL(k_m2,      dim3(288),  dim3(256), 0, stream, Ul, WUK, M2T);
  hipLaunchKernelGGL(k_qeff,    dim3(512),  dim3(256), 0, stream, Q, M2T, Qeff);
  hipLaunchKernelGGL(k_cw,      dim3(256),  dim3(256), 0, stream, Cf, WUV, CWT);
  hipLaunchKernelGGL(k_flash,   dim3(512),  dim3(256), 0, stream, Qeff, Cf, Krf, CWT, out);
}

// Round 2
// 337.965 us; speedup vs baseline: 1.9591x; 1.7584x over previous
//
#include <hip/hip_runtime.h>
#include <stdint.h>

// ---- problem constants ----
#define B_N   2
#define HQ_N  32
#define HKV_N 8
#define QL_N  1024
#define SL_N  4096
#define DH_N  128
#define ROPE_N 64
#define RANK_N 512

typedef _Float16 f16;
typedef _Float16 half8 __attribute__((ext_vector_type(8)));
typedef float floatx16 __attribute__((ext_vector_type(16)));
typedef int int2v __attribute__((ext_vector_type(2)));

union H8 { half8 h; uint64_t q[2]; };
union H4 { f16 h[4]; uint64_t q; };
union PKU { f16 h[2]; uint32_t u; };
union BFU { uint32_t u[4]; half8 h; };

// ---------------------------------------------------------------------------
// prep 1: fp32 -> fp16 convert of C_kv_t2 and K_rope_t2
// ---------------------------------------------------------------------------
__global__ __launch_bounds__(256) void k_convert(const float* __restrict__ C,
                                                 const float* __restrict__ Kr,
                                                 f16* __restrict__ Cf,
                                                 f16* __restrict__ Krf) {
  const size_t NC = (size_t)B_N * SL_N * RANK_N;            // 4194304
  size_t idx = ((size_t)blockIdx.x * 256 + threadIdx.x) * 8; // covers 8388608
  const float* src;
  f16* dst;
  if (idx < NC) { src = C + idx;        dst = Cf + idx; }
  else          { src = Kr + (idx - NC); dst = Krf + (idx - NC); }
  float4 a = *(const float4*)(src);
  float4 b = *(const float4*)(src + 4);
  H8 o;
  o.h[0] = (f16)a.x; o.h[1] = (f16)a.y; o.h[2] = (f16)a.z; o.h[3] = (f16)a.w;
  o.h[4] = (f16)b.x; o.h[5] = (f16)b.y; o.h[6] = (f16)b.z; o.h[7] = (f16)b.w;
  *(half8*)dst = o.h;
}

// ---------------------------------------------------------------------------
// prep 2: M2T2[c][d] (128 x 128, f16): Qeff2 = Q @ M2n (rotation only).
// cols 0..63 of Qeff2 = Qy @ Ul^T (nope-rot), cols 64..127 = Qx @ Ul^T (rope).
// M2T2[c][d] = M2n[d][c].
// ---------------------------------------------------------------------------
__global__ __launch_bounds__(256) void k_m2(const float* __restrict__ Ul,
                                            f16* __restrict__ M2T2) {
  int idx = blockIdx.x * 256 + threadIdx.x;   // < 16384
  int c = idx >> 7, d = idx & 127;
  float v = 0.f;
  if (c < 64) { if (d >= 64) v = Ul[c * 64 + (d - 64)]; }
  else        { if (d < 64)  v = Ul[(c - 64) * 64 + d]; }
  M2T2[idx] = (f16)v;
}

// ---------------------------------------------------------------------------
// prep 3: Qeff2 = f16(Q) @ M2n  via MFMA.  M=65536, K=128, N=128.
// grid = 512 m-tiles(128).  Direct accumulator store (coalesced 64B runs).
// ---------------------------------------------------------------------------
__global__ __launch_bounds__(256) void k_qeff(const float* __restrict__ Q,
                                              const f16* __restrict__ M2T2,
                                              f16* __restrict__ Qeff2) {
  __shared__ __align__(16) f16 qs[128 * 132];  // 33792 B
  int t = threadIdx.x;
  int wave = t >> 6, lane = t & 63, l31 = lane & 31, lhi = lane >> 5;
  size_t m0 = (size_t)blockIdx.x * 128;
  // stage Q tile (fp32 -> f16)
#pragma unroll
  for (int i = 0; i < 16; i++) {
    int flat = i * 256 + t; int row = flat >> 5, seg = flat & 31;
    float4 v = *(const float4*)(Q + (m0 + row) * DH_N + seg * 4);
    H4 o; o.h[0] = (f16)v.x; o.h[1] = (f16)v.y; o.h[2] = (f16)v.z; o.h[3] = (f16)v.w;
    *(uint64_t*)(qs + row * 132 + seg * 4) = o.q;
  }
  __syncthreads();
  floatx16 acc[4];
#pragma unroll
  for (int ct = 0; ct < 4; ct++)
#pragma unroll
    for (int r = 0; r < 16; r++) acc[ct][r] = 0.f;
#pragma unroll
  for (int kk = 0; kk < 8; ++kk) {
    H8 af;
    const uint64_t* pa = (const uint64_t*)(qs + (wave * 32 + l31) * 132 + kk * 16 + lhi * 8);
    af.q[0] = pa[0]; af.q[1] = pa[1];
#pragma unroll
    for (int ct = 0; ct < 4; ct++) {
      H8 bf; bf.h = *(const half8*)(M2T2 + (size_t)(ct * 32 + l31) * 128 + kk * 16 + lhi * 8);
      acc[ct] = __builtin_amdgcn_mfma_f32_32x32x16_f16(af.h, bf.h, acc[ct], 0, 0, 0);
    }
  }
#pragma unroll
  for (int ct = 0; ct < 4; ct++)
#pragma unroll
    for (int r = 0; r < 16; r++) {
      int row = (r & 3) + 8 * (r >> 2) + 4 * lhi;
      Qeff2[(m0 + wave * 32 + row) * 128 + ct * 32 + l31] = (f16)acc[ct][r];
    }
}

// ---------------------------------------------------------------------------
// prep 4: Kn[b][s][64] = C[b,s,:] @ W_UK^T  (f16, f32 MFMA accum).
// grid = 64 = b(2) x 32 s-tiles(128).  A-frags contiguous from Cf;
// B-frags = rows of WUK (f32, contiguous, L2-hot).
// ---------------------------------------------------------------------------
__global__ __launch_bounds__(256) void k_kn(const f16* __restrict__ Cf,
                                            const float* __restrict__ WUK,
                                            f16* __restrict__ Kn) {
  int t = threadIdx.x;
  int wave = t >> 6, lane = t & 63, l31 = lane & 31, lhi = lane >> 5;
  int b = blockIdx.x >> 5, st = blockIdx.x & 31;
  int s0 = st * 128;
  const f16* Cb = Cf + ((size_t)b * SL_N + s0 + wave * 32) * RANK_N;
  floatx16 acc[2];
#pragma unroll
  for (int ct = 0; ct < 2; ct++)
#pragma unroll
    for (int r = 0; r < 16; r++) acc[ct][r] = 0.f;
#pragma unroll 4
  for (int kk = 0; kk < 32; ++kk) {
    H8 af; af.h = *(const half8*)(Cb + (size_t)l31 * RANK_N + kk * 16 + lhi * 8);
#pragma unroll
    for (int ct = 0; ct < 2; ct++) {
      const float* wrow = WUK + (size_t)(ct * 32 + l31) * RANK_N + kk * 16 + lhi * 8;
      float4 w0 = *(const float4*)(wrow);
      float4 w1 = *(const float4*)(wrow + 4);
      H8 bf;
      bf.h[0] = (f16)w0.x; bf.h[1] = (f16)w0.y; bf.h[2] = (f16)w0.z; bf.h[3] = (f16)w0.w;
      bf.h[4] = (f16)w1.x; bf.h[5] = (f16)w1.y; bf.h[6] = (f16)w1.z; bf.h[7] = (f16)w1.w;
      acc[ct] = __builtin_amdgcn_mfma_f32_32x32x16_f16(af.h, bf.h, acc[ct], 0, 0, 0);
    }
  }
  // acc[ct]: row = s_loc = (r&3)+8*(r>>2)+4*lhi, col = j = ct*32 + l31
#pragma unroll
  for (int ct = 0; ct < 2; ct++)
#pragma unroll
    for (int r = 0; r < 16; r++) {
      int row = (r & 3) + 8 * (r >> 2) + 4 * lhi;
      Kn[((size_t)b * SL_N + s0 + wave * 32 + row) * 64 + ct * 32 + l31] = (f16)acc[ct][r];
    }
}

// ---------------------------------------------------------------------------
// prep 5: CW^T[b][c][s] = (C[b] @ W_UV)^T in fp16, via MFMA.
// ---------------------------------------------------------------------------
__global__ __launch_bounds__(256) void k_cw(const f16* __restrict__ Cf,
                                            const float* __restrict__ WUV,
                                            f16* __restrict__ CWT) {
  __shared__ float ot[32 * 132];   // 16896 B
  int t = threadIdx.x;
  int wave = t >> 6, lane = t & 63, l31 = lane & 31, lhi = lane >> 5;
  int b = blockIdx.x >> 7, st = blockIdx.x & 127;
  int s0 = st * 32;
  const f16* Cb = Cf + ((size_t)b * SL_N + s0) * RANK_N;
  floatx16 acc;
#pragma unroll
  for (int r = 0; r < 16; r++) acc[r] = 0.f;
#pragma unroll 4
  for (int kk = 0; kk < 32; ++kk) {
    H8 af; af.h = *(const half8*)(Cb + (size_t)l31 * RANK_N + kk * 16 + lhi * 8);
    H8 bf;
#pragma unroll
    for (int j = 0; j < 8; j++)
      bf.h[j] = (f16)WUV[(size_t)(kk * 16 + lhi * 8 + j) * DH_N + wave * 32 + l31];
    acc = __builtin_amdgcn_mfma_f32_32x32x16_f16(af.h, bf.h, acc, 0, 0, 0);
  }
#pragma unroll
  for (int r = 0; r < 16; r++)
    ot[((r & 3) + 8 * (r >> 2) + 4 * lhi) * 132 + wave * 32 + l31] = acc[r];
  __syncthreads();
  int c = t >> 1, sh = t & 1;
  H8 o0, o1;
#pragma unroll
  for (int j = 0; j < 8; j++) o0.h[j] = (f16)ot[(sh * 16 + j) * 132 + c];
#pragma unroll
  for (int j = 0; j < 8; j++) o1.h[j] = (f16)ot[(sh * 16 + 8 + j) * 132 + c];
  f16* dst = CWT + ((size_t)b * DH_N + c) * SL_N + s0 + sh * 16;
  *(half8*)dst = o0.h;
  *(half8*)(dst + 8) = o1.h;
}

// ---------------------------------------------------------------------------
// flash kernel, K-absorbed form: S^T K-dim = 128 (64 nope-rot + 64 rope).
// kbuf [32][KROW=132] (stride 264 B = 66 dw == 2 mod 32 -> ~2-way, free).
// All staging reg-based (4 x b128 global loads/thread/iter), commits AFTER PV
// so HBM flight covers the whole S^T+softmax+PV window.  LDS 34 KB.
// grid = 512 = (b, h, q-tile 128).
// ---------------------------------------------------------------------------
#define KROW 132
#define CROW 36

__global__ __launch_bounds__(256, 2) void k_flash(
    const f16* __restrict__ Qeff2, const f16* __restrict__ Kn,
    const f16* __restrict__ Krf, const f16* __restrict__ CWT,
    float* __restrict__ out) {
  __shared__ __align__(16) char smem[34048];
  f16* kbuf  = (f16*)smem;                    // [32][132] 8448 B
  f16* cbuf0 = (f16*)(smem + 8448);           // [128][36] 9216 B
  f16* cbuf1 = (f16*)(smem + 17664);
  float* ot  = (float*)smem;                  // epilogue [64][133] 34048 B

  int t = threadIdx.x;
  int wave = t >> 6, lane = t & 63, l31 = lane & 31, lhi = lane >> 5;
  int qt = blockIdx.x & 7; int h = (blockIdx.x >> 3) & 31; int b = blockIdx.x >> 8;
  int kv = h >> 2;
  int qloc = wave * 32 + l31;

  const f16* Knb = Kn + (size_t)b * SL_N * 64;
  const f16* Kb  = Krf + (size_t)(b * HKV_N + kv) * SL_N * ROPE_N;
  const f16* Wb  = CWT + (size_t)b * DH_N * SL_N;

  // persistent Q fragments (B-operand), K = 128
  half8 qf[8];
  {
    const f16* qrow = Qeff2 + ((size_t)(b * HQ_N + h) * QL_N + qt * 128 + qloc) * 128 + lhi * 8;
#pragma unroll
    for (int kk = 0; kk < 8; kk++) qf[kk] = *(const half8*)(qrow + kk * 16);
  }

  floatx16 oacc[4];
#pragma unroll
  for (int ct = 0; ct < 4; ct++)
#pragma unroll
    for (int r = 0; r < 16; r++) oacc[ct][r] = 0.f;
  float m_run = -1e30f, l_run = 0.f;

  int kr = t >> 3, kc = t & 7;    // K staging: row kr, 16B chunk kc (nope & rope)
  int cA = t >> 2, cch = t & 3;   // cwt staging: rows cA and 64+cA, cols cch*8

  // ---- preload tile 0 ----
  {
    H8 kn0, rp, c0, c1;
    kn0.h = *(const half8*)(Knb + (size_t)kr * 64 + kc * 8);
    rp.h  = *(const half8*)(Kb + (size_t)kr * ROPE_N + kc * 8);
    c0.h  = *(const half8*)(Wb + (size_t)cA * SL_N + cch * 8);
    c1.h  = *(const half8*)(Wb + (size_t)(64 + cA) * SL_N + cch * 8);
    uint64_t* d0 = (uint64_t*)(kbuf + kr * KROW + kc * 8);
    d0[0] = kn0.q[0]; d0[1] = kn0.q[1];
    uint64_t* d1 = (uint64_t*)(kbuf + kr * KROW + 64 + kc * 8);
    d1[0] = rp.q[0]; d1[1] = rp.q[1];
    uint64_t* e0 = (uint64_t*)(cbuf0 + cA * CROW + cch * 8);
    e0[0] = c0.q[0]; e0[1] = c0.q[1];
    uint64_t* e1 = (uint64_t*)(cbuf0 + (64 + cA) * CROW + cch * 8);
    e1[0] = c1.q[0]; e1[1] = c1.q[1];
  }
  __syncthreads();

  for (int it = 0; it < 128; ++it) {
    f16* cc = (it & 1) ? cbuf1 : cbuf0;
    f16* cn = (it & 1) ? cbuf0 : cbuf1;
    bool pre = (it + 1) < 128;
    int s0n = (it + 1) * 32;
    H8 kn1, rp, c0, c1;
    if (pre) {  // issue global loads now; commits happen after PV
      kn1.h = *(const half8*)(Knb + (size_t)(s0n + kr) * 64 + kc * 8);
      rp.h  = *(const half8*)(Kb + (size_t)(s0n + kr) * ROPE_N + kc * 8);
      c0.h  = *(const half8*)(Wb + (size_t)cA * SL_N + s0n + cch * 8);
      c1.h  = *(const half8*)(Wb + (size_t)(64 + cA) * SL_N + s0n + cch * 8);
    }

    // ---- S^T = K_eff(A) . Q^T(B), K = 128 ----
    floatx16 sa;
#pragma unroll
    for (int r = 0; r < 16; r++) sa[r] = 0.f;
    const f16* ka = kbuf + l31 * KROW + lhi * 8;
#pragma unroll
    for (int kk = 0; kk < 8; kk++) {
      H8 a0;
      const uint64_t* p0 = (const uint64_t*)(ka + kk * 16);
      a0.q[0] = p0[0]; a0.q[1] = p0[1];
      sa = __builtin_amdgcn_mfma_f32_32x32x16_f16(a0.h, qf[kk], sa, 0, 0, 0);
    }
    __syncthreads();   // barrier A: kbuf free for overwrite

    // ---- online softmax (q in lane, s in regs + partner via xor32) ----
    float mt = -1e30f;
#pragma unroll
    for (int r = 0; r < 16; r++) mt = fmaxf(mt, sa[r]);
    mt = fmaxf(mt, __shfl_xor(mt, 32, 64));
    if (__any(mt > m_run)) {   // strict defer-rescale (exact)
      float m_new = fmaxf(m_run, mt);
      float alpha = __expf(m_run - m_new);
      l_run *= alpha;
#pragma unroll
      for (int ct = 0; ct < 4; ct++)
#pragma unroll
        for (int r = 0; r < 16; r++) oacc[ct][r] *= alpha;
      m_run = m_new;
    }
    float psum = 0.f;
#pragma unroll
    for (int r = 0; r < 16; r++) { sa[r] = __expf(sa[r] - m_run); psum += sa[r]; }
    psum += __shfl_xor(psum, 32, 64);
    l_run += psum;

    // ---- build PV B-fragments in-register (pack + permlane32_swap) ----
    uint32_t pk[8];
#pragma unroll
    for (int g = 0; g < 8; ++g) {
      PKU pu; pu.h[0] = (f16)sa[2 * g]; pu.h[1] = (f16)sa[2 * g + 1];
      pk[g] = pu.u;
    }
    {
      int2v r0 = __builtin_amdgcn_permlane32_swap((int)pk[0], (int)pk[2], false, false);
      pk[0] = (uint32_t)r0.x; pk[2] = (uint32_t)r0.y;
      int2v r1 = __builtin_amdgcn_permlane32_swap((int)pk[1], (int)pk[3], false, false);
      pk[1] = (uint32_t)r1.x; pk[3] = (uint32_t)r1.y;
      int2v r2 = __builtin_amdgcn_permlane32_swap((int)pk[4], (int)pk[6], false, false);
      pk[4] = (uint32_t)r2.x; pk[6] = (uint32_t)r2.y;
      int2v r3 = __builtin_amdgcn_permlane32_swap((int)pk[5], (int)pk[7], false, false);
      pk[5] = (uint32_t)r3.x; pk[7] = (uint32_t)r3.y;
    }
    BFU b0f, b1f;
    b0f.u[0] = pk[0]; b0f.u[1] = pk[1]; b0f.u[2] = pk[2]; b0f.u[3] = pk[3];
    b1f.u[0] = pk[4]; b1f.u[1] = pk[5]; b1f.u[2] = pk[6]; b1f.u[3] = pk[7];

    // ---- PV: out^T = CW^T(A) . P^T(B), 2 ksteps ----
#pragma unroll
    for (int ks = 0; ks < 2; ++ks) {
      half8 bfh = ks ? b1f.h : b0f.h;
#pragma unroll
      for (int ct = 0; ct < 4; ct++) {
        H8 af;
        const uint64_t* pa = (const uint64_t*)(cc + (ct * 32 + l31) * CROW + ks * 16 + lhi * 8);
        af.q[0] = pa[0]; af.q[1] = pa[1];
        oacc[ct] = __builtin_amdgcn_mfma_f32_32x32x16_f16(af.h, bfh, oacc[ct], 0, 0, 0);
      }
    }

    // ---- commit staged tile i+1 (loads have had the full window to land) ----
    if (pre) {
      uint64_t* d0 = (uint64_t*)(kbuf + kr * KROW + kc * 8);
      d0[0] = kn1.q[0]; d0[1] = kn1.q[1];
      uint64_t* d1 = (uint64_t*)(kbuf + kr * KROW + 64 + kc * 8);
      d1[0] = rp.q[0]; d1[1] = rp.q[1];
      uint64_t* e0 = (uint64_t*)(cn + cA * CROW + cch * 8);
      e0[0] = c0.q[0]; e0[1] = c0.q[1];
      uint64_t* e1 = (uint64_t*)(cn + (64 + cA) * CROW + cch * 8);
      e1[0] = c1.q[0]; e1[1] = c1.q[1];
    }
    __syncthreads();   // barrier B: staged tile visible for next S^T
  }

  // ---- epilogue: two q-halves through LDS, coalesced fp32 stores ----
  float inv = 1.0f / l_run;
  float* outp = out + ((size_t)(b * HQ_N + h) * QL_N + qt * 128) * DH_N;
#pragma unroll
  for (int p = 0; p < 2; ++p) {
    __syncthreads();
    if ((qloc >> 6) == p) {
      int lr = qloc & 63;
#pragma unroll
      for (int ct = 0; ct < 4; ct++)
#pragma unroll
        for (int r = 0; r < 16; r++) {
          int c = ct * 32 + (r & 3) + 8 * (r >> 2) + 4 * lhi;
          ot[lr * 133 + c] = oacc[ct][r] * inv;
        }
    }
    __syncthreads();
#pragma unroll
    for (int i = 0; i < 8; i++) {
      int flat = i * 256 + t; int q = flat >> 5, ch = flat & 31;
      float4 v;
      v.x = ot[q * 133 + ch * 4 + 0];
      v.y = ot[q * 133 + ch * 4 + 1];
      v.z = ot[q * 133 + ch * 4 + 2];
      v.w = ot[q * 133 + ch * 4 + 3];
      *(float4*)(outp + (size_t)(p * 64 + q) * DH_N + ch * 4) = v;
    }
  }
}

// ---------------------------------------------------------------------------
extern "C" void kernel_launch(void* const* d_in, const int* in_sizes, int n_in,
                              void* d_out, int out_size, void* d_ws, size_t ws_size,
                              hipStream_t stream) {
  (void)in_sizes; (void)n_in; (void)out_size; (void)ws_size;
  const float* Q   = (const float*)d_in[0];
  const float* C   = (const float*)d_in[1];
  const float* Kr  = (const float*)d_in[2];
  const float* Ul  = (const float*)d_in[3];
  const float* WUK = (const float*)d_in[4];
  const float* WUV = (const float*)d_in[5];
  float* out = (float*)d_out;
  char* ws = (char*)d_ws;
  // workspace carve (~37 MB)
  f16* Qeff2 = (f16*)ws;                   // 16777216 B
  f16* Cf    = (f16*)(ws + 16777216);      //  8388608 B
  f16* Krf   = (f16*)(ws + 25165824);      //  8388608 B
  f16* CWT   = (f16*)(ws + 33554432);      //  2097152 B
  f16* Kn    = (f16*)(ws + 35651584);      //  1048576 B
  f16* M2T2  = (f16*)(ws + 36700160);      //    32768 B

  hipLaunchKernelGGL(k_convert, dim3(4096), dim3(256), 0, stream, C, Kr, Cf, Krf);
  hipLaunchKernelGGL(k_m2,      dim3(64),   dim3(256), 0, stream, Ul, M2T2);
  hipLaunchKernelGGL(k_qeff,    dim3(512),  dim3(256), 0, stream, Q, M2T2, Qeff2);
  hipLaunchKernelGGL(k_kn,      dim3(64),   dim3(256), 0, stream, Cf, WUK, Kn);
  hipLaunchKernelGGL(k_cw,      dim3(256),  dim3(256), 0, stream, Cf, WUV, CWT);
  hipLaunchKernelGGL(k_flash,   dim3(512),  dim3(256), 0, stream, Qeff2, Kn, Krf, CWT, out);
}